// Round 12
// baseline (116.157 us; speedup 1.0000x reference)
//
#include <hip/hip_runtime.h>

// OPU via MFMA, R12: occupancy probe (4 waves/SIMD) + double-launch direct measurement.
// Budget calibration: harness 0xAA re-poison of full 256MB ws = 43us fill INSIDE the timed
// window every round -> fixed C ~= 52us (fill + restore + presplit + gaps); main ~= 37us.
// All static pipe models (MFMA 1.3us, VALU 3.4us, VMEM/L2 <7us) sum to <6us -> main is
// stall-bound per-wave with only 2 waves/SIMD to hide it (per-XCD footprint = 4MB = exactly
// L2 => L3-latency misses ~700cyc). R12 main_v2: 1024 blocks (4/CU) x 256 thr = 4 waves/SIMD,
// block = 64x32 out tile, wave = 16-chunk k-slice (same chunk order => bit-identical out).
// Per chunk: 6 global_load_dwordx4 (literal double-buffer; R7 lesson) + 6 MFMA
// (AhBh+AlBh+AhBl per m-quadrant; AlBl dropped) + 64 quant VALU (res += rndne(acc); clip
// provably dead: |mm/16| <= 8.3^2 < 127.5). VGPR ~116 < 128 cap of launch_bounds(256,4).
// main launched TWICE (idempotent): T12 = C + 2*main_v2 -> direct duration readout.
//   T12 ~ 88-96: occupancy win (R13 drops dup -> ~70us). T12 ~ 120+: TLP not the binder.
// presplit: unchanged R11 (LDS-transposed coalesced X stores).
// Swizzle: bx%8 = (nb32&1) + 2*(mblk2&3) -> per-XCD A 2MB + B 2MB.

typedef unsigned int u32;
typedef unsigned short u16;
typedef _Float16 f16x8 __attribute__((ext_vector_type(8)));
typedef float f32x16 __attribute__((ext_vector_type(16)));

#define M_TOT 2048
#define N_TOT 1024
#define K_TOT 1024

__global__ __launch_bounds__(256) void presplit(
    const float* __restrict__ x, const float* __restrict__ w,
    const float* __restrict__ vl, const float* __restrict__ wl,
    u16* __restrict__ XH, u16* __restrict__ XL,
    u16* __restrict__ WH, u16* __restrict__ WL)
{
  __shared__ __align__(16) char lds[16384];   // [H 8KB | L 8KB], 4 chunk-planes each
  const int b = blockIdx.x;
  const int tid = threadIdx.x;

  if (b < 512) {
    // X: block = (mblk, chunk-group of 4). thread = (m_local, ch_local).
    const int mblk = b >> 4, chg = b & 15;
    const int ml = tid >> 2, chl = tid & 3;
    const int rg = ml >> 5, row = ml & 31;
    const int m = mblk * 64 + ml;
    const float* xp = x + (size_t)m * K_TOT + (chg * 4 + chl) * 16;

    u32 hp[8], lp[8];
#pragma unroll
    for (int e2 = 0; e2 < 8; ++e2) {
      u16 h2[2], l2[2];
#pragma unroll
      for (int q = 0; q < 2; ++q) {
        const int e = e2 * 2 + q;
        const float v = xp[e];
        const int xi = (int)(v + 8.0f);          // x always in [-8,7]
        const float a = v + vl[e * 16 + xi];     // j = k%16 = e (chunk-aligned)
        const _Float16 h = (_Float16)a;
        const _Float16 l = (_Float16)(a - (float)h);
        h2[q] = __builtin_bit_cast(u16, h);
        l2[q] = __builtin_bit_cast(u16, l);
      }
      hp[e2] = (u32)h2[0] | ((u32)h2[1] << 16);
      lp[e2] = (u32)l2[0] | ((u32)l2[1] << 16);
    }

    char* lh = lds + chl * 2048 + rg * 1024 + row * 16;
    *(uint4*)(lh)        = make_uint4(hp[0], hp[1], hp[2], hp[3]);  // oct0 (k0-7)
    *(uint4*)(lh + 512)  = make_uint4(hp[4], hp[5], hp[6], hp[7]);  // oct1 (k8-15)
    char* llo = lh + 8192;
    *(uint4*)(llo)       = make_uint4(lp[0], lp[1], lp[2], lp[3]);
    *(uint4*)(llo + 512) = make_uint4(lp[4], lp[5], lp[6], lp[7]);
    __syncthreads();

    const size_t gb = (size_t)(mblk * 64 + chg * 4) * 2048;
    const int off = tid * 16;
    *(uint4*)((char*)XH + gb + off)        = *(const uint4*)(lds + off);
    *(uint4*)((char*)XH + gb + off + 4096) = *(const uint4*)(lds + off + 4096);
    *(uint4*)((char*)XL + gb + off)        = *(const uint4*)(lds + 8192 + off);
    *(uint4*)((char*)XL + gb + off + 4096) = *(const uint4*)(lds + 8192 + off + 4096);
  } else {
    // W: lane runs along n -> stores already lane-contiguous.
    const int g = (b - 512) * 256 + tid;
    const int n = g & 1023, ch = g >> 10;
    const int nblk = n >> 6, ng = (n >> 5) & 1, n32 = n & 31;
    const float* wp = w + (size_t)(ch * 16) * N_TOT + n;
    u32 hp[8], lp[8];
#pragma unroll
    for (int e2 = 0; e2 < 8; ++e2) {
      u16 h2[2], l2[2];
#pragma unroll
      for (int q = 0; q < 2; ++q) {
        const int e = e2 * 2 + q;
        const float v = wp[(size_t)e * N_TOT];
        const int wi = (int)(v + 8.0f);
        const float a = (v + wl[e * 16 + wi]) * 0.0625f;  // fold 1/16 into B (exact)
        const _Float16 h = (_Float16)a;
        const _Float16 l = (_Float16)(a - (float)h);
        h2[q] = __builtin_bit_cast(u16, h);
        l2[q] = __builtin_bit_cast(u16, l);
      }
      hp[e2] = (u32)h2[0] | ((u32)h2[1] << 16);
      lp[e2] = (u32)l2[0] | ((u32)l2[1] << 16);
    }
    const size_t base = (size_t)(nblk * 64 + ch) * 1024 + ng * 512 + n32 * 8;
    *(uint4*)&WH[base]       = make_uint4(hp[0], hp[1], hp[2], hp[3]);  // oct0
    *(uint4*)&WH[base + 256] = make_uint4(hp[4], hp[5], hp[6], hp[7]);  // oct1
    *(uint4*)&WL[base]       = make_uint4(lp[0], lp[1], lp[2], lp[3]);
    *(uint4*)&WL[base + 256] = make_uint4(lp[4], lp[5], lp[6], lp[7]);
  }
}

__global__ __launch_bounds__(256, 4) void opu_main(
    const u16* __restrict__ XH, const u16* __restrict__ XL,
    const u16* __restrict__ WH, const u16* __restrict__ WL,
    float* __restrict__ out)
{
  __shared__ float cb[64 * 32];   // 8KB combine buffer

  const int tid  = threadIdx.x;
  const int wave = tid >> 6;      // k-slice: chunks [wave*16, wave*16+16)
  const int lane = tid & 63;
  const int oct  = lane >> 5;
  const int ll   = lane & 31;

  // bx%8 = (nb32&1) + 2*(mblk2&3): per-XCD A 2MB + B 2MB.
  const int bx    = blockIdx.x;                      // 0..1023
  const int nb32  = (bx & 1) + 2 * ((bx >> 3) & 15); // 0..31 (32-col groups)
  const int mblk2 = ((bx >> 1) & 3) + 4 * (bx >> 7); // 0..31 (64-row groups)
  const int nblk  = nb32 >> 1, ng = nb32 & 1;

  const size_t ck0 = (size_t)(wave * 16) * 1024;
  const u16* pAh = XH + (size_t)mblk2 * 65536 + ck0 + lane * 8;
  const u16* pAl = XL + (size_t)mblk2 * 65536 + ck0 + lane * 8;
  const u16* pBh = WH + (size_t)nblk * 65536 + ck0 + ng * 512 + lane * 8;
  const u16* pBl = WL + (size_t)nblk * 65536 + ck0 + ng * 512 + lane * 8;

  uint4 b0[6], b1[6];  // literal-indexed only (R7 scratch lesson); ~48 VGPR

#define LOADCH(dst, off)                                  \
  do {                                                    \
    (dst)[0] = *(const uint4*)(pAh + (off));              \
    (dst)[1] = *(const uint4*)(pAh + (off) + 512);        \
    (dst)[2] = *(const uint4*)(pAl + (off));              \
    (dst)[3] = *(const uint4*)(pAl + (off) + 512);        \
    (dst)[4] = *(const uint4*)(pBh + (off));              \
    (dst)[5] = *(const uint4*)(pBl + (off));              \
  } while (0)

  float res[2][16];
#pragma unroll
  for (int t = 0; t < 2; ++t)
#pragma unroll
    for (int i = 0; i < 16; ++i) res[t][i] = 0.0f;
  const f32x16 fzero = {};

#define COMPUTE(c)                                                                     \
  do {                                                                                 \
    const f16x8 Bh = __builtin_bit_cast(f16x8, (c)[4]);                                \
    const f16x8 Bl = __builtin_bit_cast(f16x8, (c)[5]);                                \
    _Pragma("unroll")                                                                  \
    for (int mt = 0; mt < 2; ++mt) {                                                   \
      const f16x8 Ah = __builtin_bit_cast(f16x8, (c)[mt]);                             \
      const f16x8 Al = __builtin_bit_cast(f16x8, (c)[2 + mt]);                         \
      f32x16 acc = __builtin_amdgcn_mfma_f32_32x32x16_f16(Ah, Bh, fzero, 0, 0, 0);     \
      acc = __builtin_amdgcn_mfma_f32_32x32x16_f16(Al, Bh, acc, 0, 0, 0);              \
      acc = __builtin_amdgcn_mfma_f32_32x32x16_f16(Ah, Bl, acc, 0, 0, 0);              \
      float* r4 = res[mt];                                                             \
      _Pragma("unroll")                                                                \
      for (int i = 0; i < 16; ++i)                                                     \
        r4[i] += __builtin_rintf(acc[i]);  /* acc = mm/16; clip provably dead */       \
    }                                                                                  \
  } while (0)

  LOADCH(b0, 0);
#pragma unroll 1
  for (int c2 = 0; c2 < 8; ++c2) {
    const size_t o = (size_t)c2 * 2048;          // 2 chunks of 1024 u16
    LOADCH(b1, o + 1024);                        // prefetch odd chunk
    COMPUTE(b0);
    if (c2 < 7) LOADCH(b0, o + 2048);            // prefetch next even chunk
    COMPUTE(b1);
  }

  // ---- combine the 4 waves' k-slices through LDS (integer-valued f32, exact) ----
#define CBIDX(mt, i) ((((mt) * 32) + ((i & 3) + 8 * (i >> 2) + 4 * oct)) * 32 + ll)
  if (wave == 0) {
#pragma unroll
    for (int mt = 0; mt < 2; ++mt)
#pragma unroll
      for (int i = 0; i < 16; ++i) cb[CBIDX(mt, i)] = res[mt][i];
  }
  __syncthreads();
  if (wave == 1) {
#pragma unroll
    for (int mt = 0; mt < 2; ++mt)
#pragma unroll
      for (int i = 0; i < 16; ++i) cb[CBIDX(mt, i)] += res[mt][i];
  }
  __syncthreads();
  if (wave == 2) {
#pragma unroll
    for (int mt = 0; mt < 2; ++mt)
#pragma unroll
      for (int i = 0; i < 16; ++i) cb[CBIDX(mt, i)] += res[mt][i];
  }
  __syncthreads();
  if (wave == 3) {
#pragma unroll
    for (int mt = 0; mt < 2; ++mt)
#pragma unroll
      for (int i = 0; i < 16; ++i) cb[CBIDX(mt, i)] += res[mt][i];
  }
  __syncthreads();

  // ---- x16 store: 64 rows x 32 cols; thread = (row, float4-col pair) ----
  const float4* cbv = (const float4*)cb;
  const int row = tid >> 2, c4 = tid & 3;
  float* orow = out + (size_t)(mblk2 * 64 + row) * N_TOT + nb32 * 32;
#pragma unroll
  for (int p = 0; p < 2; ++p) {
    float4 v = cbv[row * 8 + c4 + 4 * p];
    v.x *= 16.0f; v.y *= 16.0f; v.z *= 16.0f; v.w *= 16.0f;
    *(float4*)&orow[(c4 + 4 * p) * 4] = v;
  }
}

extern "C" void kernel_launch(void* const* d_in, const int* in_sizes, int n_in,
                              void* d_out, int out_size, void* d_ws, size_t ws_size,
                              hipStream_t stream)
{
  const float* input  = (const float*)d_in[0];
  const float* weight = (const float*)d_in[1];
  const float* vmap   = (const float*)d_in[2];
  const float* wmap   = (const float*)d_in[3];
  float* out = (float*)d_out;

  u16* XH = (u16*)d_ws;                          // 4MB (2M u16)
  u16* XL = XH + 2 * 1024 * 1024;                // 4MB
  u16* WH = XL + 2 * 1024 * 1024;                // 2MB
  u16* WL = WH + 1024 * 1024;                    // 2MB   (ws use: 12MB total)

  presplit<<<768, 256, 0, stream>>>(input, weight, vmap, wmap, XH, XL, WH, WL);

  // Launched TWICE (idempotent, identical output): T12 = C + 2*main -> direct
  // steady-state duration readout from the total. R13 drops the duplicate.
  opu_main<<<1024, 256, 0, stream>>>(XH, XL, WH, WL, out);
  opu_main<<<1024, 256, 0, stream>>>(XH, XL, WH, WL, out);
}